// Round 6
// baseline (101.690 us; speedup 1.0000x reference)
//
#include <hip/hip_runtime.h>
#include <cstddef>

#define IOU_POS_T 0.6f
#define IOU_NEG_T 0.45f
#define F_EPS 1e-6f
#define F_ALPHA 0.25f
#define F_BETA (1.0f/9.0f)
#define MAXM 64
#define BINF 3.402823466e+38f

__device__ __forceinline__ void fp_barrier(float& x) { asm volatile("" : "+v"(x)); }

// ------- kernel 0: per-block anchor bbox + zero cells & completion counter -----
__global__ void __launch_bounds__(256)
dl_bbox(const float* __restrict__ anchors, float4* __restrict__ bbb,
        unsigned long long* __restrict__ cells, unsigned int* __restrict__ ctr,
        int N, int ncells)
{
    const int tid = threadIdx.x;
    const int i = blockIdx.x * 256 + tid;
    if (blockIdx.x == 0) {
        for (int k = tid; k < ncells; k += 256) cells[k] = 0ull;
        if (tid == 0) *ctr = 0u;
    }
    float amnx = BINF, amny = BINF, amxx = -BINF, amxy = -BINF;
    if (i < N) {
        const float* a = anchors + (size_t)i * 5;
        float ax = a[0], ay = a[1], aw = a[2], al = a[3];
        amnx = ax - aw * 0.5f; amny = ay - al * 0.5f;
        amxx = ax + aw * 0.5f; amxy = ay + al * 0.5f;
    }
    #pragma unroll
    for (int off = 32; off; off >>= 1) {
        amnx = fminf(amnx, __shfl_xor(amnx, off));
        amny = fminf(amny, __shfl_xor(amny, off));
        amxx = fmaxf(amxx, __shfl_xor(amxx, off));
        amxy = fmaxf(amxy, __shfl_xor(amxy, off));
    }
    __shared__ float wbb[4][4];
    const int wave = tid >> 6;
    if ((tid & 63) == 0) { wbb[wave][0] = amnx; wbb[wave][1] = amny; wbb[wave][2] = amxx; wbb[wave][3] = amxy; }
    __syncthreads();
    if (tid == 0) {
        float bmnx = fminf(fminf(wbb[0][0], wbb[1][0]), fminf(wbb[2][0], wbb[3][0]));
        float bmny = fminf(fminf(wbb[0][1], wbb[1][1]), fminf(wbb[2][1], wbb[3][1]));
        float bmxx = fmaxf(fmaxf(wbb[0][2], wbb[1][2]), fmaxf(wbb[2][2], wbb[3][2]));
        float bmxy = fmaxf(fmaxf(wbb[0][3], wbb[1][3]), fmaxf(wbb[2][3], wbb[3][3]));
        bbb[blockIdx.x] = make_float4(bmnx, bmny, bmxx, bmxy);
    }
}

// ---------------- Pass A: per-GT argmax over anchors ---------------------------
__global__ void __launch_bounds__(256)
dl_assign(const float* __restrict__ anchors, const float* __restrict__ gt_boxes,
          const float4* __restrict__ bbb, unsigned long long* __restrict__ masks,
          unsigned long long* __restrict__ cells, int N, int M, int nblkx)
{
    const int b = blockIdx.y;
    const int tid = threadIdx.x;
    const int blk = blockIdx.x;
    const int i = blk * 256 + tid;
    __shared__ float gmnx[MAXM], gmny[MAXM], gmxx[MAXM], gmxy[MAXM], gar[MAXM];
    __shared__ unsigned long long lcell[MAXM];
    __shared__ unsigned long long smask_s;

    if (tid < 64) {   // wave 0: build GT shortlist mask vs block bbox
        bool ov = false;
        if (tid < M) {
            const float* g = gt_boxes + ((size_t)b * M + tid) * 5;
            float cx = g[0], cy = g[1], w = g[2], l = g[3];
            float hw = w * 0.5f, hl = l * 0.5f;
            float4 bb = bbb[blk];
            float wxb = fminf(bb.z, cx + hw) - fmaxf(bb.x, cx - hw);
            float wyb = fminf(bb.w, cy + hl) - fmaxf(bb.y, cy - hl);
            ov = (wxb > 0.0f) && (wyb > 0.0f);
        }
        unsigned long long bal = __ballot(ov);
        if (tid == 0) { smask_s = bal; masks[(size_t)b * nblkx + blk] = bal; }
    }
    __syncthreads();
    const unsigned long long sm = smask_s;
    if (sm == 0ull) return;

    if (tid < M) {
        const float* g = gt_boxes + ((size_t)b * M + tid) * 5;
        float cx = g[0], cy = g[1], w = g[2], l = g[3];
        float hw = w * 0.5f, hl = l * 0.5f;
        gmnx[tid] = cx - hw; gmny[tid] = cy - hl;
        gmxx[tid] = cx + hw; gmxy[tid] = cy + hl;
        gar[tid] = w * l;
        lcell[tid] = 0ull;
    }
    const bool act = i < N;
    float amnx = 0, amny = 0, amxx = 0, amxy = 0, area_a = 0.0f;
    if (act) {
        const float* a = anchors + (size_t)i * 5;
        float ax = a[0], ay = a[1], aw = a[2], al = a[3];
        amnx = ax - aw * 0.5f; amny = ay - al * 0.5f;
        amxx = ax + aw * 0.5f; amxy = ay + al * 0.5f;
        area_a = aw * al; fp_barrier(area_a);
    }
    __syncthreads();
    unsigned long long mask = act ? sm : 0ull;
    while (mask) {
        const int m = (int)__builtin_ctzll(mask); mask &= mask - 1;
        float wx = fminf(amxx, gmxx[m]) - fmaxf(amnx, gmnx[m]); wx = fmaxf(wx, 0.0f);
        float wy = fminf(amxy, gmxy[m]) - fmaxf(amny, gmny[m]); wy = fmaxf(wy, 0.0f);
        float inter = wx * wy; fp_barrier(inter);
        if (inter > 0.0f) {
            float denom = (area_a + gar[m]) - inter + F_EPS;
            float iou = inter / denom;
            // higher iou wins; equal iou -> LOWER anchor index (numpy first-occurrence)
            unsigned long long key =
                ((unsigned long long)__float_as_uint(iou) << 32) | (unsigned)(~(unsigned)i);
            atomicMax(&lcell[m], key);
        }
    }
    __syncthreads();
    if (tid < M) {
        unsigned long long v = lcell[tid];
        if (v) atomicMax(cells + (size_t)b * M + tid, v);
    }
}

// -------- Pass B: losses + last-block finalize (no dl_reduce dispatch) ---------
__global__ void __launch_bounds__(256)
dl_loss(const float* __restrict__ cls_logits, const float* __restrict__ box_preds,
        const float* __restrict__ intent_logits, const float* __restrict__ anchors,
        const float* __restrict__ gt_boxes, const int* __restrict__ gt_ints,
        const unsigned long long* __restrict__ cells,
        const unsigned long long* __restrict__ masks,
        float4* __restrict__ parts, unsigned int* __restrict__ ctr,
        float* __restrict__ out, int N, int M, int C, int nblkx)
{
    const int b = blockIdx.y;
    const int tid = threadIdx.x;
    const int blk = blockIdx.x;
    const int ibase = blk * 256;
    const int i = ibase + tid;
    const int wave = tid >> 6;
    const int total = nblkx * (int)gridDim.y;
    const unsigned long long sm = masks[(size_t)b * nblkx + blk];
    const bool act = i < N;

    __shared__ float q0[4], q1[4], q2[4], q3[4];

    if (sm == 0ull) {
        // pure-negative block: focal only, no anchor reads
        float cls_s = 0.0f;
        if (act) {
            float x = cls_logits[(size_t)b * N + i];
            float ce = fmaxf(x, 0.0f) + log1pf(expf(-fabsf(x)));
            float p = 1.0f / (1.0f + expf(-x));
            cls_s = (1.0f - F_ALPHA) * ce * (p * p);
        }
        #pragma unroll
        for (int off = 32; off; off >>= 1) cls_s += __shfl_down(cls_s, off);
        if ((tid & 63) == 0) q0[wave] = cls_s;
        __syncthreads();
        if (tid == 0)
            parts[(size_t)b * nblkx + blk] = make_float4(q0[0] + q0[1] + q0[2] + q0[3], 0.f, 0.f, 0.f);
    } else {
        __shared__ float gmnx[MAXM], gmny[MAXM], gmxx[MAXM], gmxy[MAXM], gar[MAXM];
        __shared__ float gcx[MAXM], gcy[MAXM], gw[MAXM], gl[MAXM], ga[MAXM];
        __shared__ int gint[MAXM];
        __shared__ unsigned char sforce[256];

        sforce[tid] = 0;
        unsigned long long mycell = 0;
        if (tid < M) {
            const float* g = gt_boxes + ((size_t)b * M + tid) * 5;
            float cx = g[0], cy = g[1], w = g[2], l = g[3], ang = g[4];
            float hw = w * 0.5f, hl = l * 0.5f;
            gmnx[tid] = cx - hw; gmny[tid] = cy - hl;
            gmxx[tid] = cx + hw; gmxy[tid] = cy + hl;
            gar[tid]  = w * l;
            gcx[tid] = cx; gcy[tid] = cy; gw[tid] = w; gl[tid] = l; ga[tid] = ang;
            gint[tid] = gt_ints[(size_t)b * M + tid];
            mycell = cells[(size_t)b * M + tid];
        }
        float ax = 0, ay = 0, aw = 0, al = 0, aa = 0;
        float amnx = 0, amny = 0, amxx = 0, amxy = 0, area_a = 0.0f;
        if (act) {
            const float* a = anchors + (size_t)i * 5;
            ax = a[0]; ay = a[1]; aw = a[2]; al = a[3]; aa = a[4];
            amnx = ax - aw * 0.5f; amny = ay - al * 0.5f;
            amxx = ax + aw * 0.5f; amxy = ay + al * 0.5f;
            area_a = aw * al; fp_barrier(area_a);
        }
        __syncthreads();   // sforce zeroing visible before marking
        if (tid < M) {     // forced-positive marking for anchors in this block
            float fiou = __uint_as_float((unsigned)(mycell >> 32));
            int fi = (int)(~(unsigned)mycell);
            if (fiou >= IOU_NEG_T && fi >= ibase && fi < ibase + 256) sforce[fi - ibase] = 1;
        }
        __syncthreads();

        float cls_s = 0.0f, box_s = 0.0f, int_s = 0.0f, np_ = 0.0f;
        if (act) {
            unsigned long long mask = sm;
            float bestv = 0.0f; int bestm = 0;
            while (mask) {
                const int m = (int)__builtin_ctzll(mask); mask &= mask - 1;
                float wx = fminf(amxx, gmxx[m]) - fmaxf(amnx, gmnx[m]); wx = fmaxf(wx, 0.0f);
                float wy = fminf(amxy, gmxy[m]) - fmaxf(amny, gmny[m]); wy = fmaxf(wy, 0.0f);
                float inter = wx * wy; fp_barrier(inter);
                if (inter > 0.0f) {
                    float denom = (area_a + gar[m]) - inter + F_EPS;
                    float iou = inter / denom;
                    if (iou > bestv) { bestv = iou; bestm = m; }  // strict > keeps first index
                }
            }
            const bool forced = sforce[tid] != 0;
            const bool pos = (bestv >= IOU_POS_T) || forced;
            const bool neg = bestv < IOU_NEG_T;
            if (pos || neg) {
                float x = cls_logits[(size_t)b * N + i];
                float t = pos ? 1.0f : 0.0f;
                float ce = fmaxf(x, 0.0f) - x * t + log1pf(expf(-fabsf(x)));
                float p = 1.0f / (1.0f + expf(-x));
                float p_t = p * t + (1.0f - p) * (1.0f - t);
                float a_t = F_ALPHA * t + (1.0f - F_ALPHA) * (1.0f - t);
                float om = 1.0f - p_t;
                cls_s = a_t * ce * (om * om);
            }
            if (pos) {
                np_ = 1.0f;
                const int m = bestm;
                float dx = (gcx[m] - ax) / (aw + F_EPS);
                float dy = (gcy[m] - ay) / (al + F_EPS);
                float dwv = logf(gw[m] / (aw + F_EPS) + F_EPS);
                float dlv = logf(gl[m] / (al + F_EPS) + F_EPS);
                float da = ga[m] - aa;
                float tgt6[6] = { dx, dy, dwv, dlv, sinf(da), cosf(da) };
                const float* bp = box_preds + ((size_t)b * N + i) * 6;
                #pragma unroll
                for (int k = 0; k < 6; ++k) {
                    float d = fabsf(bp[k] - tgt6[k]);
                    box_s += (d < F_BETA) ? (0.5f * d * d / F_BETA) : (d - 0.5f * F_BETA);
                }
                const float* il = intent_logits + ((size_t)b * N + i) * C;
                float mx = il[0];
                for (int c = 1; c < C; ++c) mx = fmaxf(mx, il[c]);
                float se = 0.0f;
                for (int c = 0; c < C; ++c) se += expf(il[c] - mx);
                int tg = gint[m]; tg = tg < 0 ? 0 : (tg > C - 1 ? C - 1 : tg);
                int_s = (mx + logf(se)) - il[tg];
            }
        }

        #pragma unroll
        for (int off = 32; off; off >>= 1) {
            cls_s += __shfl_down(cls_s, off);
            box_s += __shfl_down(box_s, off);
            int_s += __shfl_down(int_s, off);
            np_   += __shfl_down(np_, off);
        }
        if ((tid & 63) == 0) { q0[wave] = cls_s; q1[wave] = box_s; q2[wave] = int_s; q3[wave] = np_; }
        __syncthreads();
        if (tid == 0) {
            parts[(size_t)b * nblkx + blk] =
                make_float4(q0[0] + q0[1] + q0[2] + q0[3],
                            q1[0] + q1[1] + q1[2] + q1[3],
                            q2[0] + q2[1] + q2[2] + q2[3],
                            q3[0] + q3[1] + q3[2] + q3[3]);
        }
    }

    // ---- last-block finalize (replaces dl_reduce dispatch) ----
    __shared__ bool amLast;
    if (tid == 0) {
        __threadfence();                       // make parts store visible device-wide
        unsigned prev = atomicAdd(ctr, 1u);
        amLast = (prev == (unsigned)(total - 1));
    }
    __syncthreads();
    if (!amLast) return;
    __threadfence();                           // acquire all other blocks' parts

    float c = 0, bx = 0, it = 0, np = 0;
    for (int k = tid; k < total; k += 256) {   // identical loop to old dl_reduce
        float4 v = parts[k];
        c += v.x; bx += v.y; it += v.z; np += v.w;
    }
    #pragma unroll
    for (int off = 32; off; off >>= 1) {
        c  += __shfl_down(c, off);
        bx += __shfl_down(bx, off);
        it += __shfl_down(it, off);
        np += __shfl_down(np, off);
    }
    __syncthreads();                           // q arrays reused; prior use done
    if ((tid & 63) == 0) { q0[wave] = c; q1[wave] = bx; q2[wave] = it; q3[wave] = np; }
    __syncthreads();
    if (tid == 0) {
        float cs = q0[0] + q0[1] + q0[2] + q0[3];
        float bs = q1[0] + q1[1] + q1[2] + q1[3];
        float is = q2[0] + q2[1] + q2[2] + q2[3];
        float ns = q3[0] + q3[1] + q3[2] + q3[3];
        float denom = fmaxf(1.0f, ns);
        float cls = cs / denom, bo = bs / denom, in_ = is / denom;
        out[0] = cls + bo + 0.5f * in_;
        out[1] = cls;
        out[2] = bo;
        out[3] = in_;
        out[4] = ns;
    }
}

extern "C" void kernel_launch(void* const* d_in, const int* in_sizes, int n_in,
                              void* d_out, int out_size, void* d_ws, size_t ws_size,
                              hipStream_t stream) {
    const float* cls_logits    = (const float*)d_in[0];
    const float* box_preds     = (const float*)d_in[1];
    const float* intent_logits = (const float*)d_in[2];
    const float* anchors       = (const float*)d_in[3];
    const float* gt_boxes      = (const float*)d_in[4];
    const int*   gt_ints       = (const int*)d_in[5];

    const int N = in_sizes[3] / 5;              // anchors [N,5]
    const int B = in_sizes[0] / N;              // cls_logits [B,N,1]
    const int M = in_sizes[5] / B;              // gt_intentions [B,M]
    const int C = in_sizes[2] / in_sizes[0];    // intention_logits [B,N,C]
    const int nblkx = (N + 255) / 256;

    char* ws = (char*)d_ws;
    unsigned long long* cells = (unsigned long long*)ws;            // B*M*8
    size_t off = ((size_t)B * M * 8 + 255) & ~(size_t)255;
    float4* bbb = (float4*)(ws + off);                               // nblkx*16
    off = (off + (size_t)nblkx * 16 + 255) & ~(size_t)255;
    unsigned long long* masks = (unsigned long long*)(ws + off);     // B*nblkx*8
    off = (off + (size_t)B * nblkx * 8 + 255) & ~(size_t)255;
    float4* parts = (float4*)(ws + off);                             // B*nblkx*16
    off = (off + (size_t)B * nblkx * 16 + 255) & ~(size_t)255;
    unsigned int* ctr = (unsigned int*)(ws + off);                   // 4

    dim3 grid(nblkx, B);
    dl_bbox<<<nblkx, 256, 0, stream>>>(anchors, bbb, cells, ctr, N, B * M);
    dl_assign<<<grid, 256, 0, stream>>>(anchors, gt_boxes, bbb, masks, cells, N, M, nblkx);
    dl_loss<<<grid, 256, 0, stream>>>(cls_logits, box_preds, intent_logits, anchors,
                                      gt_boxes, gt_ints, cells, masks, parts, ctr,
                                      (float*)d_out, N, M, C, nblkx);
}